// Round 4
// baseline (31599.231 us; speedup 1.0000x reference)
//
#include <hip/hip_runtime.h>
#include <hip/hip_bf16.h>

// ---------------------------------------------------------------------------
// 2-layer tanh RNN (B=128, T=512, H=1024) + LN + vocab projection.
// Persistent fused pipeline, weight-stationary f16 fragments in VGPRs,
// per-group (16 batch rows) spin barriers with explicit agent fences.
//
//   L0 : h0[t]   = tanh(etab[x[:,t]] + Wh0·h0[t-1])        t in [0,512)
//   XP : xp[t-1] = wi1·h0[t-1] + bi1                        t in [1,512]
//   L1 : h1[t-2] = tanh(xp[t-2] + Wh1·h1[t-3])             t in [2,513]
//   PR : out[t-3] = algebraic-LN(h1[t-3]) @ (g*pw)^T + c    t in [3,514]
//
// INPUT DTYPE IS DETECTED AT RUNTIME (bf16 vs fp32): det_kernel reads emb as
// u16; fp32 data has ~50% implausible exponent fields (mantissa halves),
// bf16 ~99.6% plausible. Flag in ws steers every input load + output store.
// Internal formats are fixed: h state f16, xp fp32, etab fp32, weights f16
// (exact from bf16; one rounding from fp32 -> est. logit err ~2-4e-2).
//
// ws need: 3.01 MB. Guard: if ws_size too small, bail (out stays 0 ->
// distinct finite absmax 7.125 signature).
// ---------------------------------------------------------------------------

typedef __bf16 bf16;
typedef _Float16 f16;
typedef _Float16 f16x8 __attribute__((ext_vector_type(8)));
typedef float f32x4 __attribute__((ext_vector_type(4)));

#define TSTEPS 512
#define BATCH  128
#define HID    1024
#define NST    515

__device__ __forceinline__ f32x4 mfma16(f16x8 a, f16x8 b, f32x4 c) {
    return __builtin_amdgcn_mfma_f32_16x16x32_f16(a, b, c, 0, 0, 0);
}

// dual-dtype scalar load
__device__ __forceinline__ float ldf(const void* p, size_t i, bool f32) {
    return f32 ? ((const float*)p)[i] : (float)((const bf16*)p)[i];
}

// --------------------------- dtype detector --------------------------------
// 0 = bf16, 1 = f32. Inspects first 1024 u16 of emb (uniform nonzero values).
__global__ void det_kernel(const unsigned short* __restrict__ e, unsigned* __restrict__ flag) {
    int tid = threadIdx.x;                       // 1 block x 256
    int cnt = 0;
    for (int i = tid; i < 1024; i += 256) {
        unsigned short u = e[i];
        int ex = (u >> 7) & 0xFF;
        if ((ex >= 110 && ex <= 131) || u == 0) cnt++;
    }
    __shared__ int sh[256];
    sh[tid] = cnt; __syncthreads();
    for (int s = 128; s > 0; s >>= 1) { if (tid < s) sh[tid] += sh[tid + s]; __syncthreads(); }
    if (tid == 0) *flag = (sh[0] >= 768) ? 0u : 1u;
}

// --------------------------- setup kernels ---------------------------------
// etab[v][ch] = dot(emb[v], wi0[ch]) + bi0[ch]   fp32, 256x1024
__global__ void etab_kernel(const void* __restrict__ emb, const void* __restrict__ wi0,
                            const void* __restrict__ bi0, const unsigned* __restrict__ flag,
                            float* __restrict__ etab) {
    const bool f32 = (*flag != 0);
    int i = blockIdx.x * 256 + threadIdx.x;      // 1024 blocks
    int v = i >> 10, ch = i & 1023;
    float s = ldf(bi0, ch, f32);
    for (int e = 0; e < 512; ++e)
        s += ldf(emb, (size_t)v * 512 + e, f32) * ldf(wi0, (size_t)ch * 512 + e, f32);
    etab[i] = s;
}

// c1[v] = sum_k f16(pw[v][k]*g[k])  (matches PR fragment rounding)
// c2[v] = sum_k pw[v][k]*ln_b[k] + proj_b[v]
__global__ void c12_kernel(const void* __restrict__ pw, const void* __restrict__ g,
                           const void* __restrict__ be, const void* __restrict__ pb,
                           const unsigned* __restrict__ flag, float* __restrict__ c12) {
    const bool f32 = (*flag != 0);
    int v = threadIdx.x;                         // 1 block x 256
    float a = 0.f, b = 0.f;
    for (int k = 0; k < 1024; ++k) {
        float w = ldf(pw, (size_t)v * 1024 + k, f32);
        a += (float)(f16)(w * ldf(g, k, f32));
        b += w * ldf(be, k, f32);
    }
    c12[v] = a;
    c12[256 + v] = b + ldf(pb, v, f32);
}

// --------------------------- persistent mega kernel ------------------------
// grid 208 = 8 groups x 26 blocks; 512 thr (8 waves).
// rid = bid>>3: 0-7 L0, 8-15 XP, 16-23 L1, 24-25 PR.
__global__ __launch_bounds__(512, 2) void mega_kernel(
    const void* __restrict__ wh0, const void* __restrict__ wi1,
    const void* __restrict__ wh1, const void* __restrict__ pw,
    const void* __restrict__ lng, const void* __restrict__ bi1,
    const float* __restrict__ etab, const float* __restrict__ c12,
    const int* __restrict__ x, const unsigned* __restrict__ flag,
    f16* __restrict__ h0buf, f16* __restrict__ h1buf, float* __restrict__ xpf,
    void* __restrict__ out, unsigned* __restrict__ cnt)
{
    const bool f32io = (*flag != 0);
    const int bid  = blockIdx.x;
    const int g    = bid & 7, rid = bid >> 3;
    const int role = rid >> 3;                   // 0 L0, 1 XP, 2 L1, 3 PR
    const int slice = rid & 7;
    const int tid  = threadIdx.x;
    const int wave = tid >> 6, lane = tid & 63;
    const int n    = lane & 15, quad = lane >> 4;
    const int gbase = g * 16;
    unsigned* const myc = cnt + g * 32;

    // stationary f16 weight fragments: 32 x f16x8 = 128 VGPR
    f16x8 wf[32];
    float bias = 0.f, c1v = 0.f, c2v = 0.f;
    int ch = 0, outv = 0;
    if (role < 3) {
        ch = slice * 128 + wave * 16 + n;
        const void* W = (role == 0) ? wh0 : ((role == 1) ? wi1 : wh1);
#pragma unroll
        for (int kt = 0; kt < 32; ++kt) {
            f16x8 t;
#pragma unroll
            for (int j = 0; j < 8; ++j)
                t[j] = (f16)ldf(W, (size_t)ch * HID + kt * 32 + quad * 8 + j, f32io);
            wf[kt] = t;
        }
        if (role == 1) bias = ldf(bi1, ch, f32io);
    } else {
        int tile = slice * 8 + wave;             // 0..15
        outv = tile * 16 + n;
#pragma unroll
        for (int kt = 0; kt < 32; ++kt) {
            f16x8 t;
#pragma unroll
            for (int j = 0; j < 8; ++j) {
                int k = kt * 32 + quad * 8 + j;
                t[j] = (f16)(ldf(pw, (size_t)outv * HID + k, f32io) * ldf(lng, k, f32io));
            }
            wf[kt] = t;
        }
        c1v = c12[outv];
        c2v = c12[256 + outv];
    }

    for (int t = 0; t < NST; ++t) {
        bool active;
        const f16* rbuf;
        if (role == 0)      { active = (t < 512);            rbuf = h0buf; }
        else if (role == 1) { active = (t >= 1 && t <= 512); rbuf = h0buf; }
        else if (role == 2) { active = (t >= 2 && t <= 513); rbuf = h1buf; }
        else                { active = (t >= 3 && t <= 514); rbuf = h1buf; }

        if (active) {   // block-uniform
            const f16* A    = rbuf + ((t + 1) & 1) * (BATCH * HID);
            const f16* arow = A + (size_t)(gbase + n) * HID + quad * 8;

            float ev[4] = {0.f, 0.f, 0.f, 0.f};
            if (role == 0) {
#pragma unroll
                for (int r = 0; r < 4; ++r) {
                    int b = gbase + quad * 4 + r;
                    ev[r] = etab[(size_t)x[b * TSTEPS + t] * HID + ch];
                }
            } else if (role == 2) {
                const float* xs = xpf + (t & 1) * (BATCH * HID);
#pragma unroll
                for (int r = 0; r < 4; ++r)
                    ev[r] = xs[(size_t)(gbase + quad * 4 + r) * HID + ch];
            }

            float mu = 0.f, rs = 0.f;
            if (role == 3) {    // LN stats: lane handles row n, quarter quad
                const f16* srow = A + (size_t)(gbase + n) * HID + quad * 256;
                float sum = 0.f, sq = 0.f;
#pragma unroll
                for (int i = 0; i < 256; i += 8) {
                    f16x8 hv = *(const f16x8*)(srow + i);
#pragma unroll
                    for (int j = 0; j < 8; ++j) {
                        float e = (float)hv[j];
                        sum += e; sq += e * e;
                    }
                }
                sum += __shfl_xor(sum, 16); sq += __shfl_xor(sq, 16);
                sum += __shfl_xor(sum, 32); sq += __shfl_xor(sq, 32);
                mu = sum * (1.f / 1024.f);
                float var = sq * (1.f / 1024.f) - mu * mu;
                rs = rsqrtf(fmaxf(var, 0.f) + 1e-5f);
            }

            f32x4 a0 = {0,0,0,0}, a1 = {0,0,0,0}, a2 = {0,0,0,0}, a3 = {0,0,0,0};
#pragma unroll
            for (int kt = 0; kt < 32; kt += 4) {
                a0 = mfma16(*(const f16x8*)(arow + (kt + 0) * 32), wf[kt + 0], a0);
                a1 = mfma16(*(const f16x8*)(arow + (kt + 1) * 32), wf[kt + 1], a1);
                a2 = mfma16(*(const f16x8*)(arow + (kt + 2) * 32), wf[kt + 2], a2);
                a3 = mfma16(*(const f16x8*)(arow + (kt + 3) * 32), wf[kt + 3], a3);
            }
            f32x4 acc = (a0 + a1) + (a2 + a3);

            if (role == 0) {
                f16* dw = h0buf + (t & 1) * (BATCH * HID);
#pragma unroll
                for (int r = 0; r < 4; ++r) {
                    int b = gbase + quad * 4 + r;
                    dw[(size_t)b * HID + ch] = (f16)tanhf(acc[r] + ev[r]);
                }
            } else if (role == 1) {
                float* dw = xpf + ((t + 1) & 1) * (BATCH * HID);
#pragma unroll
                for (int r = 0; r < 4; ++r) {
                    int b = gbase + quad * 4 + r;
                    dw[(size_t)b * HID + ch] = acc[r] + bias;
                }
            } else if (role == 2) {
                f16* dw = h1buf + (t & 1) * (BATCH * HID);
#pragma unroll
                for (int r = 0; r < 4; ++r) {
                    int b = gbase + quad * 4 + r;
                    dw[(size_t)b * HID + ch] = (f16)tanhf(acc[r] + ev[r]);
                }
            } else {
                int s = t - 3;
#pragma unroll
                for (int r = 0; r < 4; ++r) {
                    int m = quad * 4 + r;
                    float mm = __shfl(mu, m), rr = __shfl(rs, m);
                    float lv = rr * acc[r] - rr * mm * c1v + c2v;
                    size_t oi = ((size_t)(gbase + m) * TSTEPS + s) * 256 + outv;
                    if (f32io) ((float*)out)[oi] = lv;
                    else       ((bf16*)out)[oi]  = (bf16)lv;
                }
            }
        }

        // ---- per-group barrier (26 blocks), explicit agent fences ----
        __syncthreads();
        __threadfence();    // release: push stores device-visible
        if (tid == 0) {
            __hip_atomic_fetch_add(myc, 1u, __ATOMIC_RELAXED, __HIP_MEMORY_SCOPE_AGENT);
            const unsigned tgt = 26u * (unsigned)(t + 1);
            while (__hip_atomic_load(myc, __ATOMIC_RELAXED, __HIP_MEMORY_SCOPE_AGENT) < tgt)
                __builtin_amdgcn_s_sleep(1);
        }
        __syncthreads();
        __threadfence();    // acquire: invalidate before next reads
    }
}

// --------------------------- launch -----------------------------------------
extern "C" void kernel_launch(void* const* d_in, const int* in_sizes, int n_in,
                              void* d_out, int out_size, void* d_ws, size_t ws_size,
                              hipStream_t stream) {
    const void* emb    = d_in[0];
    const void* wi0    = d_in[1];
    const void* bi0    = d_in[2];
    const void* wh0    = d_in[3];
    const void* wi1    = d_in[4];
    const void* bi1    = d_in[5];
    const void* wh1    = d_in[6];
    const void* ln_g   = d_in[7];
    const void* ln_b   = d_in[8];
    const void* proj_w = d_in[9];
    const void* proj_b = d_in[10];
    const int*  x      = (const int*)d_in[11];
    char* ws = (char*)d_ws;

    // ws map (bytes), total 3,151,936
    float*    etab  = (float*)(ws + 0);             // 1,048,576
    float*    c12   = (float*)(ws + 1048576);       // 2,048
    unsigned* flag  = (unsigned*)(ws + 1050624);    // 64
    f16*      h0buf = (f16*)(ws + 1050688);         // 524,288 ping-pong
    f16*      h1buf = (f16*)(ws + 1574976);         // 524,288 ping-pong
    float*    xpf   = (float*)(ws + 2099264);       // 1,048,576 ping-pong
    unsigned* cnt   = (unsigned*)(ws + 3147840);    // 4,096
    if (ws_size < 3151936u) return;  // bail signature: out stays 0

    // zero flag + h/xp ping-pongs + counters: [1050624, 3151936)
    hipMemsetAsync(ws + 1050624, 0, 3151936 - 1050624, stream);

    det_kernel<<<1, 256, 0, stream>>>((const unsigned short*)emb, flag);
    etab_kernel<<<1024, 256, 0, stream>>>(emb, wi0, bi0, flag, etab);
    c12_kernel<<<1, 256, 0, stream>>>(proj_w, ln_g, ln_b, proj_b, flag, c12);
    mega_kernel<<<208, 512, 0, stream>>>(wh0, wi1, wh1, proj_w, ln_g, bi1,
                                         etab, c12, x, flag,
                                         h0buf, h1buf, xpf, d_out, cnt);
}

// Round 5
// 17048.218 us; speedup vs baseline: 1.8535x; 1.8535x over previous
//
#include <hip/hip_runtime.h>
#include <hip/hip_bf16.h>

// ---------------------------------------------------------------------------
// 2-layer tanh RNN (B=128, T=512, H=1024) + LN + vocab projection.
// Persistent fused pipeline, weight-stationary f16 fragments in VGPRs,
// per-group (16 batch rows) spin barriers.
//
//   L0 : h0[t]   = tanh(etab[x[:,t]] + Wh0·h0[t-1])        t in [0,512)
//   XP : xp[t-1] = wi1·h0[t-1] + bi1                        t in [1,512]
//   L1 : h1[t-2] = tanh(xp[t-2] + Wh1·h1[t-3])             t in [2,513]
//   PR : out[t-3] = algebraic-LN(h1[t-3]) @ (g*pw)^T + c    t in [3,514]
//
// CROSS-BLOCK COHERENCE (the R4->R5 fix): h0buf/h1buf/xpf and the barrier
// counter are accessed ONLY via agent-scope RELAXED atomic loads/stores,
// which compile to sc0|sc1 global ops on gfx950 — they bypass L1/L2 and hit
// the coherent Infinity Cache directly. NO __threadfence() anywhere: R4's
// per-step agent fences emitted buffer_wbl2/buffer_inv (full 4MB L2 scans,
// ~59 us/step of the 61 us/step total). Ordering now comes from
// __syncthreads()'s vmcnt(0) drain (sc1 stores acked at the coherence point)
// before the sc1 counter add; consumer sc1 loads issue after the spin.
// Read-only data (etab, x, weights) stays plain-cached in L2 across steps.
//
// INPUT DTYPE DETECTED AT RUNTIME (bf16 vs fp32), flag steers all I/O.
// ws need: 3.01 MB.
// ---------------------------------------------------------------------------

typedef __bf16 bf16;
typedef _Float16 f16;
typedef _Float16 f16x8 __attribute__((ext_vector_type(8)));
typedef float f32x4 __attribute__((ext_vector_type(4)));
typedef unsigned long long u64;

#define TSTEPS 512
#define BATCH  128
#define HID    1024
#define NST    515

__device__ __forceinline__ f32x4 mfma16(f16x8 a, f16x8 b, f32x4 c) {
    return __builtin_amdgcn_mfma_f32_16x16x32_f16(a, b, c, 0, 0, 0);
}

// ---- agent-coherent (sc0|sc1, L1/L2-bypassing) data movement helpers ----
__device__ __forceinline__ f16x8 lda16(const f16* p) {   // 16B via 2x8B
    union { u64 u[2]; f16x8 v; } c;
    c.u[0] = __hip_atomic_load((const u64*)p,     __ATOMIC_RELAXED, __HIP_MEMORY_SCOPE_AGENT);
    c.u[1] = __hip_atomic_load((const u64*)p + 1, __ATOMIC_RELAXED, __HIP_MEMORY_SCOPE_AGENT);
    return c.v;
}
__device__ __forceinline__ void sth2(f16* p, f16 v) {    // 2B coherent store
    union { f16 f; unsigned short s; } c; c.f = v;
    __hip_atomic_store((unsigned short*)p, c.s, __ATOMIC_RELAXED, __HIP_MEMORY_SCOPE_AGENT);
}
__device__ __forceinline__ void stf4(float* p, float v) { // 4B coherent store
    union { float f; unsigned u; } c; c.f = v;
    __hip_atomic_store((unsigned*)p, c.u, __ATOMIC_RELAXED, __HIP_MEMORY_SCOPE_AGENT);
}
__device__ __forceinline__ float ldf4c(const float* p) {  // 4B coherent load
    union { float f; unsigned u; } c;
    c.u = __hip_atomic_load((const unsigned*)p, __ATOMIC_RELAXED, __HIP_MEMORY_SCOPE_AGENT);
    return c.f;
}

// dual-dtype scalar load (read-only inputs, plain cached)
__device__ __forceinline__ float ldf(const void* p, size_t i, bool f32) {
    return f32 ? ((const float*)p)[i] : (float)((const bf16*)p)[i];
}

// --------------------------- dtype detector --------------------------------
__global__ void det_kernel(const unsigned short* __restrict__ e, unsigned* __restrict__ flag) {
    int tid = threadIdx.x;                       // 1 block x 256
    int cnt = 0;
    for (int i = tid; i < 1024; i += 256) {
        unsigned short u = e[i];
        int ex = (u >> 7) & 0xFF;
        if ((ex >= 110 && ex <= 131) || u == 0) cnt++;
    }
    __shared__ int sh[256];
    sh[tid] = cnt; __syncthreads();
    for (int s = 128; s > 0; s >>= 1) { if (tid < s) sh[tid] += sh[tid + s]; __syncthreads(); }
    if (tid == 0) *flag = (sh[0] >= 768) ? 0u : 1u;
}

// --------------------------- setup kernels ---------------------------------
__global__ void etab_kernel(const void* __restrict__ emb, const void* __restrict__ wi0,
                            const void* __restrict__ bi0, const unsigned* __restrict__ flag,
                            float* __restrict__ etab) {
    const bool f32 = (*flag != 0);
    int i = blockIdx.x * 256 + threadIdx.x;      // 1024 blocks
    int v = i >> 10, ch = i & 1023;
    float s = ldf(bi0, ch, f32);
    for (int e = 0; e < 512; ++e)
        s += ldf(emb, (size_t)v * 512 + e, f32) * ldf(wi0, (size_t)ch * 512 + e, f32);
    etab[i] = s;
}

__global__ void c12_kernel(const void* __restrict__ pw, const void* __restrict__ g,
                           const void* __restrict__ be, const void* __restrict__ pb,
                           const unsigned* __restrict__ flag, float* __restrict__ c12) {
    const bool f32 = (*flag != 0);
    int v = threadIdx.x;                         // 1 block x 256
    float a = 0.f, b = 0.f;
    for (int k = 0; k < 1024; ++k) {
        float w = ldf(pw, (size_t)v * 1024 + k, f32);
        a += (float)(f16)(w * ldf(g, k, f32));
        b += w * ldf(be, k, f32);
    }
    c12[v] = a;
    c12[256 + v] = b + ldf(pb, v, f32);
}

// --------------------------- persistent mega kernel ------------------------
// grid 208 = 8 groups x 26 blocks; 512 thr (8 waves).
// rid = bid>>3: 0-7 L0, 8-15 XP, 16-23 L1, 24-25 PR.
__global__ __launch_bounds__(512, 2) void mega_kernel(
    const void* __restrict__ wh0, const void* __restrict__ wi1,
    const void* __restrict__ wh1, const void* __restrict__ pw,
    const void* __restrict__ lng, const void* __restrict__ bi1,
    const float* __restrict__ etab, const float* __restrict__ c12,
    const int* __restrict__ x, const unsigned* __restrict__ flag,
    f16* __restrict__ h0buf, f16* __restrict__ h1buf, float* __restrict__ xpf,
    void* __restrict__ out, unsigned* __restrict__ cnt)
{
    const bool f32io = (*flag != 0);
    const int bid  = blockIdx.x;
    const int g    = bid & 7, rid = bid >> 3;
    const int role = rid >> 3;                   // 0 L0, 1 XP, 2 L1, 3 PR
    const int slice = rid & 7;
    const int tid  = threadIdx.x;
    const int wave = tid >> 6, lane = tid & 63;
    const int n    = lane & 15, quad = lane >> 4;
    const int gbase = g * 16;
    unsigned* const myc = cnt + g * 32;

    // stationary f16 weight fragments: 32 x f16x8 = 128 VGPR
    f16x8 wf[32];
    float bias = 0.f, c1v = 0.f, c2v = 0.f;
    int ch = 0, outv = 0;
    if (role < 3) {
        ch = slice * 128 + wave * 16 + n;
        const void* W = (role == 0) ? wh0 : ((role == 1) ? wi1 : wh1);
#pragma unroll
        for (int kt = 0; kt < 32; ++kt) {
            f16x8 t;
#pragma unroll
            for (int j = 0; j < 8; ++j)
                t[j] = (f16)ldf(W, (size_t)ch * HID + kt * 32 + quad * 8 + j, f32io);
            wf[kt] = t;
        }
        if (role == 1) bias = ldf(bi1, ch, f32io);
    } else {
        int tile = slice * 8 + wave;             // 0..15
        outv = tile * 16 + n;
#pragma unroll
        for (int kt = 0; kt < 32; ++kt) {
            f16x8 t;
#pragma unroll
            for (int j = 0; j < 8; ++j) {
                int k = kt * 32 + quad * 8 + j;
                t[j] = (f16)(ldf(pw, (size_t)outv * HID + k, f32io) * ldf(lng, k, f32io));
            }
            wf[kt] = t;
        }
        c1v = c12[outv];
        c2v = c12[256 + outv];
    }

    for (int t = 0; t < NST; ++t) {
        bool active;
        f16* rbuf;
        if (role == 0)      { active = (t < 512);            rbuf = h0buf; }
        else if (role == 1) { active = (t >= 1 && t <= 512); rbuf = h0buf; }
        else if (role == 2) { active = (t >= 2 && t <= 513); rbuf = h1buf; }
        else                { active = (t >= 3 && t <= 514); rbuf = h1buf; }

        if (active) {   // block-uniform
            const f16* A    = rbuf + ((t + 1) & 1) * (BATCH * HID);
            const f16* arow = A + (size_t)(gbase + n) * HID + quad * 8;

            float ev[4] = {0.f, 0.f, 0.f, 0.f};
            if (role == 0) {
#pragma unroll
                for (int r = 0; r < 4; ++r) {
                    int b = gbase + quad * 4 + r;
                    ev[r] = etab[(size_t)x[b * TSTEPS + t] * HID + ch];
                }
            } else if (role == 2) {
                const float* xs = xpf + (t & 1) * (BATCH * HID);
#pragma unroll
                for (int r = 0; r < 4; ++r)
                    ev[r] = ldf4c(xs + (size_t)(gbase + quad * 4 + r) * HID + ch);
            }

            float mu = 0.f, rs = 0.f;
            if (role == 3) {    // LN stats: lane handles row n, quarter quad
                const f16* srow = A + (size_t)(gbase + n) * HID + quad * 256;
                float sum = 0.f, sq = 0.f;
#pragma unroll
                for (int i = 0; i < 256; i += 8) {
                    f16x8 hv = lda16(srow + i);
#pragma unroll
                    for (int j = 0; j < 8; ++j) {
                        float e = (float)hv[j];
                        sum += e; sq += e * e;
                    }
                }
                sum += __shfl_xor(sum, 16); sq += __shfl_xor(sq, 16);
                sum += __shfl_xor(sum, 32); sq += __shfl_xor(sq, 32);
                mu = sum * (1.f / 1024.f);
                float var = sq * (1.f / 1024.f) - mu * mu;
                rs = rsqrtf(fmaxf(var, 0.f) + 1e-5f);
            }

            f32x4 a0 = {0,0,0,0}, a1 = {0,0,0,0}, a2 = {0,0,0,0}, a3 = {0,0,0,0};
#pragma unroll
            for (int kt = 0; kt < 32; kt += 4) {
                a0 = mfma16(lda16(arow + (kt + 0) * 32), wf[kt + 0], a0);
                a1 = mfma16(lda16(arow + (kt + 1) * 32), wf[kt + 1], a1);
                a2 = mfma16(lda16(arow + (kt + 2) * 32), wf[kt + 2], a2);
                a3 = mfma16(lda16(arow + (kt + 3) * 32), wf[kt + 3], a3);
            }
            f32x4 acc = (a0 + a1) + (a2 + a3);

            if (role == 0) {
                f16* dw = h0buf + (t & 1) * (BATCH * HID);
#pragma unroll
                for (int r = 0; r < 4; ++r) {
                    int b = gbase + quad * 4 + r;
                    sth2(dw + (size_t)b * HID + ch, (f16)tanhf(acc[r] + ev[r]));
                }
            } else if (role == 1) {
                float* dw = xpf + ((t + 1) & 1) * (BATCH * HID);
#pragma unroll
                for (int r = 0; r < 4; ++r) {
                    int b = gbase + quad * 4 + r;
                    stf4(dw + (size_t)b * HID + ch, acc[r] + bias);
                }
            } else if (role == 2) {
                f16* dw = h1buf + (t & 1) * (BATCH * HID);
#pragma unroll
                for (int r = 0; r < 4; ++r) {
                    int b = gbase + quad * 4 + r;
                    sth2(dw + (size_t)b * HID + ch, (f16)tanhf(acc[r] + ev[r]));
                }
            } else {
                int s = t - 3;
#pragma unroll
                for (int r = 0; r < 4; ++r) {
                    int m = quad * 4 + r;
                    float mm = __shfl(mu, m), rr = __shfl(rs, m);
                    float lv = rr * acc[r] - rr * mm * c1v + c2v;
                    size_t oi = ((size_t)(gbase + m) * TSTEPS + s) * 256 + outv;
                    if (f32io) ((float*)out)[oi] = lv;
                    else       ((bf16*)out)[oi]  = (bf16)lv;
                }
            }
        }

        // ---- per-group barrier (26 blocks); NO cache-maintenance fences ----
        // __syncthreads() drains this block's sc1 stores (vmcnt 0 -> acked at
        // the coherence point); the sc1 counter add is therefore ordered
        // after them; consumers' sc1 loads issue only after the spin.
        __syncthreads();
        if (tid == 0) {
            __hip_atomic_fetch_add(myc, 1u, __ATOMIC_RELAXED, __HIP_MEMORY_SCOPE_AGENT);
            const unsigned tgt = 26u * (unsigned)(t + 1);
            while (__hip_atomic_load(myc, __ATOMIC_RELAXED, __HIP_MEMORY_SCOPE_AGENT) < tgt)
                __builtin_amdgcn_s_sleep(1);
        }
        __syncthreads();
    }
}

// --------------------------- launch -----------------------------------------
extern "C" void kernel_launch(void* const* d_in, const int* in_sizes, int n_in,
                              void* d_out, int out_size, void* d_ws, size_t ws_size,
                              hipStream_t stream) {
    const void* emb    = d_in[0];
    const void* wi0    = d_in[1];
    const void* bi0    = d_in[2];
    const void* wh0    = d_in[3];
    const void* wi1    = d_in[4];
    const void* bi1    = d_in[5];
    const void* wh1    = d_in[6];
    const void* ln_g   = d_in[7];
    const void* ln_b   = d_in[8];
    const void* proj_w = d_in[9];
    const void* proj_b = d_in[10];
    const int*  x      = (const int*)d_in[11];
    char* ws = (char*)d_ws;

    // ws map (bytes), total 3,151,936
    float*    etab  = (float*)(ws + 0);             // 1,048,576
    float*    c12   = (float*)(ws + 1048576);       // 2,048
    unsigned* flag  = (unsigned*)(ws + 1050624);    // 64
    f16*      h0buf = (f16*)(ws + 1050688);         // 524,288 ping-pong
    f16*      h1buf = (f16*)(ws + 1574976);         // 524,288 ping-pong
    float*    xpf   = (float*)(ws + 2099264);       // 1,048,576 ping-pong
    unsigned* cnt   = (unsigned*)(ws + 3147840);    // 4,096
    if (ws_size < 3151936u) return;  // bail signature: out stays 0

    // zero flag + h/xp ping-pongs + counters: [1050624, 3151936)
    hipMemsetAsync(ws + 1050624, 0, 3151936 - 1050624, stream);

    det_kernel<<<1, 256, 0, stream>>>((const unsigned short*)emb, flag);
    etab_kernel<<<1024, 256, 0, stream>>>(emb, wi0, bi0, flag, etab);
    c12_kernel<<<1, 256, 0, stream>>>(proj_w, ln_g, ln_b, proj_b, flag, c12);
    mega_kernel<<<208, 512, 0, stream>>>(wh0, wi1, wh1, proj_w, ln_g, bi1,
                                         etab, c12, x, flag,
                                         h0buf, h1buf, xpf, d_out, cnt);
}

// Round 6
// 3881.891 us; speedup vs baseline: 8.1402x; 4.3917x over previous
//
#include <hip/hip_runtime.h>
#include <hip/hip_bf16.h>

// ---------------------------------------------------------------------------
// 2-layer tanh RNN (B=128, T=512, H=1024) + LN + vocab projection.
// Persistent fused pipeline, weight-stationary f16 fragments in VGPRs,
// per-group (16 batch rows) spin barriers.
//
//   L0 : h0[t]   = tanh(etab[x[:,t]] + Wh0·h0[t-1])        t in [0,512)
//   XP : xp[t-1] = wi1·h0[t-1] + bi1                        t in [1,512]
//   L1 : h1[t-2] = tanh(xp[t-2] + Wh1·h1[t-3])             t in [2,513]
//   PR : out[t-3] = algebraic-LN(h1[t-3]) @ (g*pw)^T + c    t in [3,514]
//
// COHERENCE: h0buf/h1buf/xpf + barrier counters accessed only via agent-scope
// RELAXED atomics (sc0|sc1 -> Infinity Cache direct). No __threadfence()
// (R4: per-step wbL2/invL2 scans were ~59 us/step).
//
// R5->R6: LDS-STAGE THE A-TILE. R5 had every wave re-reading the identical
// 32 KB A-tile via sc1 (L1/L2-bypass) loads -> 256 KB/block/step, ~53 MB/step
// of IF reads = the dominant cost (MfmaUtil 1%, everything else idle).
// Now 512 threads stage A once (32 KB, coherent 16B loads -> LDS, row stride
// 1032 f16 => only 2-way bank aliasing, free), all waves ds_read_b128
// fragments; PR's LN stats also read the LDS copy. 8x less IF traffic.
//
// INPUT DTYPE DETECTED AT RUNTIME (bf16 vs fp32), flag steers all I/O.
// ws need: 3.01 MB.
// ---------------------------------------------------------------------------

typedef __bf16 bf16;
typedef _Float16 f16;
typedef _Float16 f16x8 __attribute__((ext_vector_type(8)));
typedef float f32x4 __attribute__((ext_vector_type(4)));
typedef unsigned long long u64;

#define TSTEPS 512
#define BATCH  128
#define HID    1024
#define NST    515

__device__ __forceinline__ f32x4 mfma16(f16x8 a, f16x8 b, f32x4 c) {
    return __builtin_amdgcn_mfma_f32_16x16x32_f16(a, b, c, 0, 0, 0);
}

// ---- agent-coherent (sc0|sc1, L1/L2-bypassing) helpers ----
__device__ __forceinline__ f16x8 lda16(const f16* p) {   // 16B via 2x8B
    union { u64 u[2]; f16x8 v; } c;
    c.u[0] = __hip_atomic_load((const u64*)p,     __ATOMIC_RELAXED, __HIP_MEMORY_SCOPE_AGENT);
    c.u[1] = __hip_atomic_load((const u64*)p + 1, __ATOMIC_RELAXED, __HIP_MEMORY_SCOPE_AGENT);
    return c.v;
}
__device__ __forceinline__ void sth2(f16* p, f16 v) {    // 2B coherent store
    union { f16 f; unsigned short s; } c; c.f = v;
    __hip_atomic_store((unsigned short*)p, c.s, __ATOMIC_RELAXED, __HIP_MEMORY_SCOPE_AGENT);
}
__device__ __forceinline__ void stf4(float* p, float v) { // 4B coherent store
    union { float f; unsigned u; } c; c.f = v;
    __hip_atomic_store((unsigned*)p, c.u, __ATOMIC_RELAXED, __HIP_MEMORY_SCOPE_AGENT);
}
__device__ __forceinline__ float ldf4c(const float* p) {  // 4B coherent load
    union { float f; unsigned u; } c;
    c.u = __hip_atomic_load((const unsigned*)p, __ATOMIC_RELAXED, __HIP_MEMORY_SCOPE_AGENT);
    return c.f;
}

// dual-dtype scalar load (read-only inputs, plain cached)
__device__ __forceinline__ float ldf(const void* p, size_t i, bool f32) {
    return f32 ? ((const float*)p)[i] : (float)((const bf16*)p)[i];
}

// --------------------------- dtype detector --------------------------------
__global__ void det_kernel(const unsigned short* __restrict__ e, unsigned* __restrict__ flag) {
    int tid = threadIdx.x;                       // 1 block x 256
    int cnt = 0;
    for (int i = tid; i < 1024; i += 256) {
        unsigned short u = e[i];
        int ex = (u >> 7) & 0xFF;
        if ((ex >= 110 && ex <= 131) || u == 0) cnt++;
    }
    __shared__ int sh[256];
    sh[tid] = cnt; __syncthreads();
    for (int s = 128; s > 0; s >>= 1) { if (tid < s) sh[tid] += sh[tid + s]; __syncthreads(); }
    if (tid == 0) *flag = (sh[0] >= 768) ? 0u : 1u;
}

// --------------------------- setup kernels ---------------------------------
__global__ void etab_kernel(const void* __restrict__ emb, const void* __restrict__ wi0,
                            const void* __restrict__ bi0, const unsigned* __restrict__ flag,
                            float* __restrict__ etab) {
    const bool f32 = (*flag != 0);
    int i = blockIdx.x * 256 + threadIdx.x;      // 1024 blocks
    int v = i >> 10, ch = i & 1023;
    float s = ldf(bi0, ch, f32);
    for (int e = 0; e < 512; ++e)
        s += ldf(emb, (size_t)v * 512 + e, f32) * ldf(wi0, (size_t)ch * 512 + e, f32);
    etab[i] = s;
}

__global__ void c12_kernel(const void* __restrict__ pw, const void* __restrict__ g,
                           const void* __restrict__ be, const void* __restrict__ pb,
                           const unsigned* __restrict__ flag, float* __restrict__ c12) {
    const bool f32 = (*flag != 0);
    int v = threadIdx.x;                         // 1 block x 256
    float a = 0.f, b = 0.f;
    for (int k = 0; k < 1024; ++k) {
        float w = ldf(pw, (size_t)v * 1024 + k, f32);
        a += (float)(f16)(w * ldf(g, k, f32));
        b += w * ldf(be, k, f32);
    }
    c12[v] = a;
    c12[256 + v] = b + ldf(pb, v, f32);
}

// --------------------------- persistent mega kernel ------------------------
// grid 208 = 8 groups x 26 blocks; 512 thr (8 waves).
// rid = bid>>3: 0-7 L0, 8-15 XP, 16-23 L1, 24-25 PR.
__global__ __launch_bounds__(512, 2) void mega_kernel(
    const void* __restrict__ wh0, const void* __restrict__ wi1,
    const void* __restrict__ wh1, const void* __restrict__ pw,
    const void* __restrict__ lng, const void* __restrict__ bi1,
    const float* __restrict__ etab, const float* __restrict__ c12,
    const int* __restrict__ x, const unsigned* __restrict__ flag,
    f16* __restrict__ h0buf, f16* __restrict__ h1buf, float* __restrict__ xpf,
    void* __restrict__ out, unsigned* __restrict__ cnt)
{
    const bool f32io = (*flag != 0);
    const int bid  = blockIdx.x;
    const int g    = bid & 7, rid = bid >> 3;
    const int role = rid >> 3;                   // 0 L0, 1 XP, 2 L1, 3 PR
    const int slice = rid & 7;
    const int tid  = threadIdx.x;
    const int wave = tid >> 6, lane = tid & 63;
    const int n    = lane & 15, quad = lane >> 4;
    const int gbase = g * 16;
    unsigned* const myc = cnt + g * 32;

    // A-tile staging buffer: 16 rows x 1032 (pad: stride 516 words -> worst
    // 2-way bank aliasing, free). 33 KB LDS.
    __shared__ f16 As[16][1032];

    // stationary f16 weight fragments: 32 x f16x8 = 128 VGPR
    f16x8 wf[32];
    float bias = 0.f, c1v = 0.f, c2v = 0.f;
    int ch = 0, outv = 0;
    if (role < 3) {
        ch = slice * 128 + wave * 16 + n;
        const void* W = (role == 0) ? wh0 : ((role == 1) ? wi1 : wh1);
#pragma unroll
        for (int kt = 0; kt < 32; ++kt) {
            f16x8 t;
#pragma unroll
            for (int j = 0; j < 8; ++j)
                t[j] = (f16)ldf(W, (size_t)ch * HID + kt * 32 + quad * 8 + j, f32io);
            wf[kt] = t;
        }
        if (role == 1) bias = ldf(bi1, ch, f32io);
    } else {
        int tile = slice * 8 + wave;             // 0..15
        outv = tile * 16 + n;
#pragma unroll
        for (int kt = 0; kt < 32; ++kt) {
            f16x8 t;
#pragma unroll
            for (int j = 0; j < 8; ++j) {
                int k = kt * 32 + quad * 8 + j;
                t[j] = (f16)(ldf(pw, (size_t)outv * HID + k, f32io) * ldf(lng, k, f32io));
            }
            wf[kt] = t;
        }
        c1v = c12[outv];
        c2v = c12[256 + outv];
    }

    for (int t = 0; t < NST; ++t) {
        bool active;
        f16* rbuf;
        if (role == 0)      { active = (t < 512);            rbuf = h0buf; }
        else if (role == 1) { active = (t >= 1 && t <= 512); rbuf = h0buf; }
        else if (role == 2) { active = (t >= 2 && t <= 513); rbuf = h1buf; }
        else                { active = (t >= 3 && t <= 514); rbuf = h1buf; }

        if (active) {   // block-uniform
            // ---- cooperative A-tile stage: 32 KB, once per block ----
            const f16* Abase = rbuf + ((t + 1) & 1) * (BATCH * HID)
                             + (size_t)gbase * HID;
#pragma unroll
            for (int it = 0; it < 4; ++it) {
                int idx = it * 512 + tid;        // 2048 chunks of 16B
                int row = idx >> 7, col = (idx & 127) << 3;
                f16x8 v = lda16(Abase + (size_t)row * HID + col);
                *(f16x8*)&As[row][col] = v;
            }

            // epilogue operands (independent of staging)
            float ev[4] = {0.f, 0.f, 0.f, 0.f};
            if (role == 0) {
#pragma unroll
                for (int r = 0; r < 4; ++r) {
                    int b = gbase + quad * 4 + r;
                    ev[r] = etab[(size_t)x[b * TSTEPS + t] * HID + ch];
                }
            } else if (role == 2) {
                const float* xs = xpf + (t & 1) * (BATCH * HID);
#pragma unroll
                for (int r = 0; r < 4; ++r)
                    ev[r] = ldf4c(xs + (size_t)(gbase + quad * 4 + r) * HID + ch);
            }

            __syncthreads();    // A-tile visible to all waves

            float mu = 0.f, rs = 0.f;
            if (role == 3) {    // LN stats from the LDS copy
                const f16* srow = &As[n][quad * 256];
                float sum = 0.f, sq = 0.f;
#pragma unroll
                for (int i = 0; i < 256; i += 8) {
                    f16x8 hv = *(const f16x8*)(srow + i);
#pragma unroll
                    for (int j = 0; j < 8; ++j) {
                        float e = (float)hv[j];
                        sum += e; sq += e * e;
                    }
                }
                sum += __shfl_xor(sum, 16); sq += __shfl_xor(sq, 16);
                sum += __shfl_xor(sum, 32); sq += __shfl_xor(sq, 32);
                mu = sum * (1.f / 1024.f);
                float var = sq * (1.f / 1024.f) - mu * mu;
                rs = rsqrtf(fmaxf(var, 0.f) + 1e-5f);
            }

            const f16* arow = &As[n][quad * 8];
            f32x4 a0 = {0,0,0,0}, a1 = {0,0,0,0}, a2 = {0,0,0,0}, a3 = {0,0,0,0};
#pragma unroll
            for (int kt = 0; kt < 32; kt += 4) {
                a0 = mfma16(*(const f16x8*)(arow + (kt + 0) * 32), wf[kt + 0], a0);
                a1 = mfma16(*(const f16x8*)(arow + (kt + 1) * 32), wf[kt + 1], a1);
                a2 = mfma16(*(const f16x8*)(arow + (kt + 2) * 32), wf[kt + 2], a2);
                a3 = mfma16(*(const f16x8*)(arow + (kt + 3) * 32), wf[kt + 3], a3);
            }
            f32x4 acc = (a0 + a1) + (a2 + a3);

            if (role == 0) {
                f16* dw = h0buf + (t & 1) * (BATCH * HID);
#pragma unroll
                for (int r = 0; r < 4; ++r) {
                    int b = gbase + quad * 4 + r;
                    sth2(dw + (size_t)b * HID + ch, (f16)tanhf(acc[r] + ev[r]));
                }
            } else if (role == 1) {
                float* dw = xpf + ((t + 1) & 1) * (BATCH * HID);
#pragma unroll
                for (int r = 0; r < 4; ++r) {
                    int b = gbase + quad * 4 + r;
                    stf4(dw + (size_t)b * HID + ch, acc[r] + bias);
                }
            } else if (role == 2) {
                f16* dw = h1buf + (t & 1) * (BATCH * HID);
#pragma unroll
                for (int r = 0; r < 4; ++r) {
                    int b = gbase + quad * 4 + r;
                    sth2(dw + (size_t)b * HID + ch, (f16)tanhf(acc[r] + ev[r]));
                }
            } else {
                int s = t - 3;
#pragma unroll
                for (int r = 0; r < 4; ++r) {
                    int m = quad * 4 + r;
                    float mm = __shfl(mu, m), rr = __shfl(rs, m);
                    float lv = rr * acc[r] - rr * mm * c1v + c2v;
                    size_t oi = ((size_t)(gbase + m) * TSTEPS + s) * 256 + outv;
                    if (f32io) ((float*)out)[oi] = lv;
                    else       ((bf16*)out)[oi]  = (bf16)lv;
                }
            }
        }

        // ---- per-group barrier (26 blocks); no cache-maintenance ops ----
        __syncthreads();    // drains sc1 stores (vmcnt 0, acked at IF)
        if (tid == 0) {
            __hip_atomic_fetch_add(myc, 1u, __ATOMIC_RELAXED, __HIP_MEMORY_SCOPE_AGENT);
            const unsigned tgt = 26u * (unsigned)(t + 1);
            while (__hip_atomic_load(myc, __ATOMIC_RELAXED, __HIP_MEMORY_SCOPE_AGENT) < tgt)
                __builtin_amdgcn_s_sleep(1);
        }
        __syncthreads();
    }
}

// --------------------------- launch -----------------------------------------
extern "C" void kernel_launch(void* const* d_in, const int* in_sizes, int n_in,
                              void* d_out, int out_size, void* d_ws, size_t ws_size,
                              hipStream_t stream) {
    const void* emb    = d_in[0];
    const void* wi0    = d_in[1];
    const void* bi0    = d_in[2];
    const void* wh0    = d_in[3];
    const void* wi1    = d_in[4];
    const void* bi1    = d_in[5];
    const void* wh1    = d_in[6];
    const void* ln_g   = d_in[7];
    const void* ln_b   = d_in[8];
    const void* proj_w = d_in[9];
    const void* proj_b = d_in[10];
    const int*  x      = (const int*)d_in[11];
    char* ws = (char*)d_ws;

    // ws map (bytes), total 3,151,936
    float*    etab  = (float*)(ws + 0);             // 1,048,576
    float*    c12   = (float*)(ws + 1048576);       // 2,048
    unsigned* flag  = (unsigned*)(ws + 1050624);    // 64
    f16*      h0buf = (f16*)(ws + 1050688);         // 524,288 ping-pong
    f16*      h1buf = (f16*)(ws + 1574976);         // 524,288 ping-pong
    float*    xpf   = (float*)(ws + 2099264);       // 1,048,576 ping-pong
    unsigned* cnt   = (unsigned*)(ws + 3147840);    // 4,096
    if (ws_size < 3151936u) return;  // bail signature: out stays 0

    // zero flag + h/xp ping-pongs + counters: [1050624, 3151936)
    hipMemsetAsync(ws + 1050624, 0, 3151936 - 1050624, stream);

    det_kernel<<<1, 256, 0, stream>>>((const unsigned short*)emb, flag);
    etab_kernel<<<1024, 256, 0, stream>>>(emb, wi0, bi0, flag, etab);
    c12_kernel<<<1, 256, 0, stream>>>(proj_w, ln_g, ln_b, proj_b, flag, c12);
    mega_kernel<<<208, 512, 0, stream>>>(wh0, wi1, wh1, proj_w, ln_g, bi1,
                                         etab, c12, x, flag,
                                         h0buf, h1buf, xpf, d_out, cnt);
}